// Round 2
// baseline (102.368 us; speedup 1.0000x reference)
//
#include <hip/hip_runtime.h>
#include <cstdint>

// RNN: B=8192, T=2048, I=1, H=2, O=1. One thread per batch element.
//
// R5: runtime-certified truncation. Evidence so far: absmax == 0.0 on both
// R3/R4 benches => the exact full-scan path is active => sigma >= 0.9966
// (rigorous fading-memory bound unusable). But the *empirical* dynamics
// contract (tanh saturation: per-step Jacobian diag(1-h^2) W_hh). So:
//   - Run the last KE=384 steps with TWO trajectories sharing sg inputs:
//       A from h=0 (r=1,1),  B from h=(0.95,-0.95) (r=0.05,1.95).
//   - If |A-B|_inf <= 4e-5 at the end, the init has washed out =>
//     A ~= exact state to ~4e-4 (threshold is 8.75e-3). Use A.
//   - Lanes with len <= 384 are EXACT (masked prefix holds A at h=0).
//   - Lanes with K <= 384 are rigorously covered (sigma^384 <= 1e-3).
//   - Any other lane (certificate failed): per-lane exact full scan.
// Correctness is therefore unconditional; the certificate only gates speed.
//
// Masked prefix (t < 0): A is held at exactly r=1 via post-step cndmask
// (replaces the old m0-constant trick, which only holds r=1 up to ~2e-6/step
// of constant-fold rounding and can drift when the masked map is unstable).
// B is garbage during masked steps -- irrelevant, those lanes skip the check.
//
// r-state per step (unit i): u = sg - A*r;  r' = rcp(exp2(u) + 0.5);
// h = 1 - r; sg folds S*(b_ih+b_hh) + rowsum(A) - 1, S = 2*log2(e).

#define T_LEN 2048
#define KE 384  // certified-truncation window (multiple of 16)

__device__ __forceinline__ float fast_exp2(float x) {
#if __has_builtin(__builtin_amdgcn_exp2f)
  return __builtin_amdgcn_exp2f(x);
#else
  return exp2f(x);
#endif
}

__device__ __forceinline__ float fast_rcp(float x) {
#if __has_builtin(__builtin_amdgcn_rcpf)
  return __builtin_amdgcn_rcpf(x);
#else
  return 1.0f / x;
#endif
}

// One step in r-state. sg already includes the +rowsum-1 constant fold.
__device__ __forceinline__ void rnn_step_r(float sg0, float sg1,
                                           float A00, float A01,
                                           float A10, float A11,
                                           float& r0, float& r1) {
  float u0 = fmaf(-A00, r0, fmaf(-A01, r1, sg0));
  float u1 = fmaf(-A10, r0, fmaf(-A11, r1, sg1));
  float e0 = fast_exp2(u0);
  float e1 = fast_exp2(u1);
  r0 = fast_rcp(e0 + 0.5f);
  r1 = fast_rcp(e1 + 0.5f);
}

__global__ __launch_bounds__(64) void rnn_scan(
    const float* __restrict__ x, const int* __restrict__ lengths,
    const float* __restrict__ wih, const float* __restrict__ whh,
    const float* __restrict__ bih, const float* __restrict__ bhh,
    const float* __restrict__ fcw, const float* __restrict__ fcb,
    float* __restrict__ out) {
  const int b = blockIdx.x * 64 + threadIdx.x;

  const float S = 2.885390081777926f;  // 2*log2(e)
  const float wa = whh[0], wb = whh[1], wc = whh[2], wd = whh[3];
  const float A00 = S * wa, A01 = S * wb;
  const float A10 = S * wc, A11 = S * wd;
  const float sw0 = S * wih[0];
  const float sw1 = S * wih[1];
  // sc folds: S*(b_ih + b_hh) + rowsum(A) - 1
  const float sc0 = fmaf(S, bih[0] + bhh[0], A00 + A01 - 1.0f);
  const float sc1 = fmaf(S, bih[1] + bhh[1], A10 + A11 - 1.0f);
  const float m0 = A00 + A01 - 1.0f;  // masked-step sg constant (fast path)
  const float m1 = A10 + A11 - 1.0f;

  // sigma_max of 2x2 W_hh (exact closed form), slightly inflated for fp.
  const float g11 = wa * wa + wc * wc;
  const float g22 = wb * wb + wd * wd;
  const float g12 = wa * wb + wc * wd;
  const float half_tr = 0.5f * (g11 + g22);
  const float half_df = 0.5f * (g11 - g22);
  const float s2 = half_tr + sqrtf(half_df * half_df + g12 * g12);
  const float sigma = sqrtf(s2) * 1.0002f;

  int K;
  if (sigma > 1e-4f && sigma < 0.999f) {
    // sigma^K <= 1e-3  ->  K = ceil(ln(1e-3)/ln(sigma)); ln(1e-3) = -6.9078
    K = (int)ceilf(-6.9078f / logf(sigma));
    if (K < 8) K = 8;
  } else if (!(sigma > 1e-4f)) {
    K = 8;  // sigma ~ 0
  } else {
    K = 1 << 20;  // near/above 1: no rigorous truncation
  }
  if (!(sigma == sigma)) K = 1 << 20;  // NaN guard

  const int len = lengths[b];  // in [1, 2047]
  const float* __restrict__ xp = x + (size_t)b * T_LEN;

  float r0 = 1.0f, r1 = 1.0f;  // h = 0

  if (K <= 256) {
    // ---- rigorous fast path: uniform Kp steps, masked prefix ----
    const int Kp = (K + 15) & ~15;  // multiple of 16, <= 256
    const int t0 = len - Kp;        // may be negative

    float xs[16];
#pragma unroll
    for (int i = 0; i < 16; ++i) {
      const int t = t0 + i;
      xs[i] = xp[min(max(t, 0), T_LEN - 1)];
    }
    for (int blk = 0; blk < Kp; blk += 16) {
      float xn[16];
#pragma unroll
      for (int i = 0; i < 16; ++i) {
        const int t = t0 + blk + 16 + i;
        xn[i] = xp[min(max(t, 0), T_LEN - 1)];
      }
#pragma unroll
      for (int i = 0; i < 16; ++i) {
        const int t = t0 + blk + i;
        const bool v = t >= 0;
        const float sg0 = v ? fmaf(sw0, xs[i], sc0) : m0;  // off-chain mask
        const float sg1 = v ? fmaf(sw1, xs[i], sc1) : m1;
        rnn_step_r(sg0, sg1, A00, A01, A10, A11, r0, r1);
      }
#pragma unroll
      for (int i = 0; i < 16; ++i) xs[i] = xn[i];
    }
  } else {
    // ---- certified truncation: dual trajectory over last KE steps ----
    const int t0 = len - KE;  // may be negative
    float rA0 = 1.0f, rA1 = 1.0f;      // A: h = 0
    float rB0 = 0.05f, rB1 = 1.95f;    // B: h = (0.95, -0.95)

    float xs[16];
#pragma unroll
    for (int i = 0; i < 16; ++i) {
      const int t = t0 + i;
      xs[i] = xp[min(max(t, 0), T_LEN - 1)];
    }
    for (int blk = 0; blk < KE; blk += 16) {
      float xn[16];
#pragma unroll
      for (int i = 0; i < 16; ++i) {
        const int t = t0 + blk + 16 + i;
        xn[i] = xp[min(max(t, 0), T_LEN - 1)];
      }
#pragma unroll
      for (int i = 0; i < 16; ++i) {
        const int t = t0 + blk + i;
        const bool v = t >= 0;
        const float sg0 = fmaf(sw0, xs[i], sc0);
        const float sg1 = fmaf(sw1, xs[i], sc1);
        // A: step, then exact hold at r=1 while t<0 (off the trans chain,
        // cndmask only).
        float a0 = rA0, a1 = rA1;
        rnn_step_r(sg0, sg1, A00, A01, A10, A11, a0, a1);
        rA0 = v ? a0 : 1.0f;
        rA1 = v ? a1 : 1.0f;
        // B: probe trajectory, no masking (unused for len<=KE lanes).
        rnn_step_r(sg0, sg1, A00, A01, A10, A11, rB0, rB1);
      }
#pragma unroll
      for (int i = 0; i < 16; ++i) xs[i] = xn[i];
    }

    const float diff = fmaxf(fabsf(rA0 - rB0), fabsf(rA1 - rB1));
    const bool ok = (len <= KE)      // A is exact (full history covered)
                    || (K <= KE)     // rigorous: sigma^KE <= 1e-3
                    || (diff <= 4e-5f);  // runtime washout certificate

    if (!ok) {
      // exact per-lane fallback (rare; exec-masked, skipped if execz)
      rA0 = 1.0f;
      rA1 = 1.0f;
      for (int t = 0; t < len; ++t) {
        rnn_step_r(fmaf(sw0, xp[t], sc0), fmaf(sw1, xp[t], sc1),
                   A00, A01, A10, A11, rA0, rA1);
      }
    }
    r0 = rA0;
    r1 = rA1;
  }

  // out = fc.(1 - r) + fcb = (fc0 + fc1 + fcb) - fc0*r0 - fc1*r1
  const float fc0 = fcw[0], fc1 = fcw[1];
  const float csum = fc0 + fc1 + fcb[0];
  out[b] = fmaf(-fc0, r0, fmaf(-fc1, r1, csum));
}

extern "C" void kernel_launch(void* const* d_in, const int* in_sizes, int n_in,
                              void* d_out, int out_size, void* d_ws,
                              size_t ws_size, hipStream_t stream) {
  const float* x = (const float*)d_in[0];
  const int* lengths = (const int*)d_in[1];
  const float* wih = (const float*)d_in[2];
  const float* whh = (const float*)d_in[3];
  const float* bih = (const float*)d_in[4];
  const float* bhh = (const float*)d_in[5];
  const float* fcw = (const float*)d_in[6];
  const float* fcb = (const float*)d_in[7];
  float* out = (float*)d_out;

  const int B = 8192;
  rnn_scan<<<B / 64, 64, 0, stream>>>(x, lengths, wih, whh, bih, bhh, fcw,
                                      fcb, out);
}